// Round 1
// baseline (378.682 us; speedup 1.0000x reference)
//
#include <hip/hip_runtime.h>
#include <hip/hip_bf16.h>

#define EPS 1e-6f

// One thread per edge (grid-stride). Streaming loads coalesced; x gathers are
// random 12B reads served mostly by L3 (x = 24 MB < 256 MB Infinity Cache).
// Reduction: per-thread fp32 -> wave64 shfl -> LDS -> one atomicAdd per block.
__global__ __launch_bounds__(256) void hookean_energy_kernel(
    const float* __restrict__ x,      // [V,3]
    const int*   __restrict__ idx,    // [E,2] int32
    const float* __restrict__ l0,     // [E]
    const float* __restrict__ k,      // [E]
    float* __restrict__ out,          // [1], pre-zeroed
    int E)
{
    float acc = 0.0f;
    const int stride = gridDim.x * blockDim.x;
    for (int e = blockIdx.x * blockDim.x + threadIdx.x; e < E; e += stride) {
        int2 ij = ((const int2*)idx)[e];              // coalesced 8B load
        const float* xi = x + 3ll * ij.x;
        const float* xj = x + 3ll * ij.y;
        float dx = xi[0] - xj[0];
        float dy = xi[1] - xj[1];
        float dz = xi[2] - xj[2];
        float q  = dx*dx + dy*dy + dz*dz;
        float l  = sqrtf(q + EPS);
        float dl = l - l0[e];
        acc += k[e] * dl * dl;
    }
    acc *= 0.5f;

    // wave64 butterfly reduce
    #pragma unroll
    for (int off = 32; off > 0; off >>= 1)
        acc += __shfl_down(acc, off, 64);

    __shared__ float wave_sums[4];                    // 256 threads = 4 waves
    const int lane = threadIdx.x & 63;
    const int wave = threadIdx.x >> 6;
    if (lane == 0) wave_sums[wave] = acc;
    __syncthreads();

    if (threadIdx.x == 0) {
        float s = wave_sums[0] + wave_sums[1] + wave_sums[2] + wave_sums[3];
        atomicAdd(out, s);                            // device-scope by default
    }
}

extern "C" void kernel_launch(void* const* d_in, const int* in_sizes, int n_in,
                              void* d_out, int out_size, void* d_ws, size_t ws_size,
                              hipStream_t stream) {
    const float* x   = (const float*)d_in[0];
    const int*   idx = (const int*)d_in[1];
    const float* l0  = (const float*)d_in[2];
    const float* k   = (const float*)d_in[3];
    float* out = (float*)d_out;

    const int E = in_sizes[2];  // l0 has E elements (indices is E*2 flat)

    // d_out is re-poisoned to 0xAA before every launch — zero it.
    hipMemsetAsync(out, 0, sizeof(float) * out_size, stream);

    const int block = 256;
    const int grid  = 4096;  // 1M threads, ~8 edges/thread; plenty of waves to hide gather latency
    hookean_energy_kernel<<<grid, block, 0, stream>>>(x, idx, l0, k, out, E);
}